// Round 21
// baseline (57.649 us; speedup 1.0000x reference)
//
#include <hip/hip_runtime.h>
#include <math.h>

// CircleLoss, symmetric-triangle bf16-MFMA, 8-wave (512-thread) blocks.
//   R20 lesson: fragments must read from LDS (L2-direct regresses). R21 lever:
//   waves/SIMD 2 -> 4 at CONSTANT staging ratio and phase count — same 128x128
//   tile, same one-shot A+B staging (64KB), same 2 barriers, but 8 waves of
//   64x32 sub-tiles. acc halves to [4][2] -> VGPR <= 128 (launch_bounds 512,4)
//   -> 2 blocks/CU = 16 waves/CU. Epilogue: R18's validated u-form + f32x2
//   packed (P,N) accumulation (DIRECT sums, no T-P cancellation).
//   Slots: row = 4CT+wc (wc 0..3), col = 256+2RT+wr; row g's written set is
//   exactly [4*Rg,256) u [256,256+2*Rg) — rowloss reads exactly that.
//   No atomics, deterministic. Transposed partial[slot][row] packed bf16.
// ws (256MB avail): 2MB featsN + 12.6MB partial[384][B] + 1KB blocksum.

#define DIM 128
#define NSLOT 384
typedef short bf16x8 __attribute__((ext_vector_type(8)));
typedef float f32x4 __attribute__((ext_vector_type(4)));
typedef float f32x2 __attribute__((ext_vector_type(2)));

#if __has_builtin(__builtin_amdgcn_exp2f)
#define EXP2F __builtin_amdgcn_exp2f
#else
#define EXP2F exp2f
#endif

__device__ __forceinline__ unsigned short f2bf(float f) {
    unsigned int b = __float_as_uint(f);
    unsigned int r = (b + 0x7FFFu + ((b >> 16) & 1u)) >> 16;   // RN-even
    return (unsigned short)r;
}
__device__ __forceinline__ unsigned int packPN(float p, float n) {
    return (unsigned int)f2bf(p) | ((unsigned int)f2bf(n) << 16);
}

// ---------------- Kernel 1: normalize + quantize ----------------
__global__ void prep_kernel(const float* __restrict__ feats,
                            unsigned int* __restrict__ featsN, int B) {
    int wave = (blockIdx.x * blockDim.x + threadIdx.x) >> 6;
    int lane = threadIdx.x & 63;
    if (wave >= B) return;
    const float2* rp = (const float2*)(feats + (size_t)wave * DIM);
    float2 v = rp[lane];
    float s = v.x * v.x + v.y * v.y;
#pragma unroll
    for (int off = 32; off; off >>= 1) s += __shfl_xor(s, off);
    float inv = rsqrtf(s);
    featsN[(size_t)wave * 64 + lane] =
        (unsigned int)f2bf(v.x * inv) | ((unsigned int)f2bf(v.y * inv) << 16);
}

// ---------------- Kernel 2: triangular fused MFMA + masked exp ----------------
// 2080 blocks = tile pairs (RT,CT), RT<=CT. 8 waves (2 wr x 4 wc), wave=64x32.
__global__ __launch_bounds__(512, 4) void circle_main_kernel(
    const unsigned short* __restrict__ featsN, const int* __restrict__ labels,
    unsigned int* __restrict__ partial, int B) {
    __shared__ unsigned char smem[65536] __attribute__((aligned(16)));
    unsigned char* Al = smem;
    unsigned char* Bl = smem + 32768;
    unsigned int* tbuf = (unsigned int*)smem;   // 8*64*17*4B = 34816B, aliased

    // ---- unrank bid -> (RT, CT), RT <= CT ----
    int bid = blockIdx.x;
    int RT = (int)((129.0 - sqrt(16641.0 - 8.0 * (double)bid)) * 0.5);
    RT = RT < 0 ? 0 : (RT > 63 ? 63 : RT);
    while (64 * RT - (RT * (RT - 1)) / 2 > bid) --RT;
    while (64 * (RT + 1) - ((RT + 1) * RT) / 2 <= bid) ++RT;
    const int CT = RT + (bid - (64 * RT - (RT * (RT - 1)) / 2));
    const bool diag = (RT == CT);

    const int tid = threadIdx.x;
    const int lane = tid & 63;
    const int wv = tid >> 6;          // 0..7
    const int wr = wv >> 2;           // 0..1 : rows [wr*64, +64)
    const int wc = wv & 3;            // 0..3 : cols [wc*32, +32)
    const int lg = lane >> 4;
    const int l15 = lane & 15;

    // ---- stage A (RT rows) and B (CT rows), 4-bit XOR swizzle ----
    {
        const int r0 = tid >> 4, c = tid & 15;   // r0 in [0,32)
#pragma unroll
        for (int it = 0; it < 4; ++it) {
            int row = it * 32 + r0;
            int swz = ((c ^ (row & 15)) << 4);
            int4 va = *(const int4*)(featsN + (size_t)(RT * 128 + row) * DIM + c * 8);
            *(int4*)(Al + row * 256 + swz) = va;
            int4 vb = *(const int4*)(featsN + (size_t)(CT * 128 + row) * DIM + c * 8);
            *(int4*)(Bl + row * 256 + swz) = vb;
        }
    }
    __syncthreads();

    // ---- MFMA: 32 per wave (4m x 2n x 4k) ----
    f32x4 acc[4][2];
#pragma unroll
    for (int m = 0; m < 4; ++m)
#pragma unroll
        for (int n = 0; n < 2; ++n) acc[m][n] = (f32x4){0.f, 0.f, 0.f, 0.f};
#pragma unroll
    for (int kk = 0; kk < 4; ++kk) {
        bf16x8 af[4], bfr[2];
#pragma unroll
        for (int m = 0; m < 4; ++m) {
            int row = wr * 64 + m * 16 + l15;
            af[m] = __builtin_bit_cast(bf16x8,
                *(const int4*)(Al + row * 256 + (((kk * 4 + lg) ^ (row & 15)) << 4)));
        }
#pragma unroll
        for (int n = 0; n < 2; ++n) {
            int row = wc * 32 + n * 16 + l15;
            bfr[n] = __builtin_bit_cast(bf16x8,
                *(const int4*)(Bl + row * 256 + (((kk * 4 + lg) ^ (row & 15)) << 4)));
        }
#pragma unroll
        for (int m = 0; m < 4; ++m)
#pragma unroll
            for (int n = 0; n < 2; ++n)
                acc[m][n] = __builtin_amdgcn_mfma_f32_16x16x32_bf16(
                    af[m], bfr[n], acc[m][n], 0, 0, 0);
    }

    // ---- epilogue: u-form, packed (P,N) accumulation ----
    const int rowbase = RT * 128 + wr * 64;
    const int colbase = CT * 128 + wc * 32;
    const float S2 = 46.166241308446828f;   // 32*log2(e)
    const float C2 = -23.083120654223414f;  // -0.5*S2

    int lc[2], lr[4][4];
#pragma unroll
    for (int n = 0; n < 2; ++n) lc[n] = labels[colbase + n * 16 + l15];
#pragma unroll
    for (int m = 0; m < 4; ++m)
#pragma unroll
        for (int r = 0; r < 4; ++r) lr[m][r] = labels[rowbase + m * 16 + lg * 4 + r];

    f32x2 rPN[4][4];
    f32x2 cPN[2] = {(f32x2){0.f, 0.f}, (f32x2){0.f, 0.f}};

    if (diag) {
#pragma unroll
        for (int m = 0; m < 4; ++m) {
#pragma unroll
            for (int r = 0; r < 4; ++r) {
                const int grow = rowbase + m * 16 + lg * 4 + r;
                const int lrow = lr[m][r];
                f32x2 s_ = (f32x2){0.f, 0.f};
#pragma unroll
                for (int n = 0; n < 2; ++n) {
                    float sim = acc[m][n][r];
                    bool same = (lrow == lc[n]);
                    float u = same ? (1.25f - sim) : (sim + 0.25f);
                    float e2 = fmaxf(u, 0.f) * fmaf(S2, u, C2);
                    float v = EXP2F(e2);
                    bool self = (grow == colbase + n * 16 + l15);
                    v = self ? 0.f : v;             // self excluded everywhere
                    float pv = same ? v : 0.f;
                    s_ += (f32x2){pv, v - pv};      // {P, N} packed add
                }
                rPN[m][r] = s_;
            }
        }
    } else {
#pragma unroll
        for (int m = 0; m < 4; ++m) {
#pragma unroll
            for (int r = 0; r < 4; ++r) {
                const int lrow = lr[m][r];
                f32x2 s_ = (f32x2){0.f, 0.f};
#pragma unroll
                for (int n = 0; n < 2; ++n) {
                    float sim = acc[m][n][r];
                    bool same = (lrow == lc[n]);
                    float u = same ? (1.25f - sim) : (sim + 0.25f);
                    float e2 = fmaxf(u, 0.f) * fmaf(S2, u, C2);
                    float v = EXP2F(e2);
                    float pv = same ? v : 0.f;
                    f32x2 w = (f32x2){pv, v - pv};  // exact: pv is v or 0
                    s_ += w;
                    cPN[n] += w;
                }
                rPN[m][r] = s_;
            }
        }
    }

    // ---- col partials (off-diag only): shuffle reduce over lane groups ----
    // slot = 256 + 2RT + wr; waves with same wr write disjoint col ranges (wc).
    if (!diag) {
#pragma unroll
        for (int n = 0; n < 2; ++n) {
            float p = cPN[n].x, n_ = cPN[n].y;
            p += __shfl_xor(p, 16); p += __shfl_xor(p, 32);
            n_ += __shfl_xor(n_, 16); n_ += __shfl_xor(n_, 32);
            if (lg == 0) {
                int gcol = colbase + n * 16 + l15;
                partial[(size_t)(256 + RT * 2 + wr) * B + gcol] = packPN(p, n_);
            }
        }
    }

    // ---- row partials: LDS transpose reduce; slot = 4CT + wc ----
    __syncthreads();   // all Al/Bl fragment reads complete before reuse
    {
        unsigned int* T = tbuf + wv * 64 * 17;
#pragma unroll
        for (int m = 0; m < 4; ++m)
#pragma unroll
            for (int r = 0; r < 4; ++r)
                T[(m * 16 + lg * 4 + r) * 17 + l15] = packPN(rPN[m][r].x, rPN[m][r].y);
    }
    __syncthreads();
    {
        const unsigned int* T = tbuf + wv * 64 * 17 + lane * 17;
        float p = 0.f, n_ = 0.f;
#pragma unroll
        for (int c = 0; c < 16; ++c) {
            unsigned int v = T[c];
            p += __uint_as_float(v << 16);
            n_ += __uint_as_float(v & 0xFFFF0000u);
        }
        int grow = RT * 128 + wr * 64 + lane;
        partial[(size_t)(CT * 4 + wc) * B + grow] = packPN(p, n_);
    }
}

// ---------------- Kernel 3: per-row log1p(p*n), parallel over slots ----------------
// Row g (tile Rg = g>>7) written slots: [4*Rg, 256) u [256, 256+2*Rg).
__global__ void rowloss_kernel(const unsigned int* __restrict__ partial,
                               double* __restrict__ blocksum, int B) {
    __shared__ float2 sdata[64][4];
    int tid = threadIdx.x;
    int r6 = tid & 63, q = tid >> 6;
    int row = blockIdx.x * 64 + r6;
    int Rg = row >> 7;
    float p = 0.f, n = 0.f;
    for (int c = 4 * Rg + q; c < 256; c += 4) {
        unsigned int v = partial[(size_t)c * B + row];
        p += __uint_as_float(v << 16);
        n += __uint_as_float(v & 0xFFFF0000u);
    }
    for (int c = 256 + q; c < 256 + 2 * Rg; c += 4) {
        unsigned int v = partial[(size_t)c * B + row];
        p += __uint_as_float(v << 16);
        n += __uint_as_float(v & 0xFFFF0000u);
    }
    sdata[r6][q] = make_float2(p, n);
    __syncthreads();
    if (q == 0) {
        float2 a0 = sdata[r6][0], a1 = sdata[r6][1];
        float2 a2 = sdata[r6][2], a3 = sdata[r6][3];
        double pf = (double)(a0.x + a1.x + a2.x + a3.x);
        double nf = (double)(a0.y + a1.y + a2.y + a3.y);
        double l = log1p(pf * nf);
#pragma unroll
        for (int off = 32; off; off >>= 1) l += __shfl_xor(l, off);
        if (r6 == 0) blocksum[blockIdx.x] = l;
    }
}

__global__ void final_kernel(const double* __restrict__ blocksum,
                             float* __restrict__ out, int nblk, int B) {
    __shared__ double sdata[128];
    int tid = threadIdx.x;
    sdata[tid] = (tid < nblk) ? blocksum[tid] : 0.0;
    __syncthreads();
    for (int s = 64; s; s >>= 1) {
        if (tid < s) sdata[tid] += sdata[tid + s];
        __syncthreads();
    }
    if (tid == 0) out[0] = (float)(sdata[0] / (double)B);
}

extern "C" void kernel_launch(void* const* d_in, const int* in_sizes, int n_in,
                              void* d_out, int out_size, void* d_ws, size_t ws_size,
                              hipStream_t stream) {
    const float* feats = (const float*)d_in[0];
    const int* labels = (const int*)d_in[1];
    float* out = (float*)d_out;
    int B = in_sizes[1];  // 8192

    // ws: featsN bf16 [B][128] (2MB) | partial u32 [384][B] (12.6MB) | blocksum
    unsigned int* featsN = (unsigned int*)d_ws;
    size_t off1 = ((size_t)B * DIM * 2 + 255) & ~(size_t)255;
    unsigned int* partial = (unsigned int*)((char*)d_ws + off1);
    size_t off2 = off1 + (((size_t)B * NSLOT * sizeof(unsigned int) + 255) & ~(size_t)255);
    double* blocksum = (double*)((char*)d_ws + off2);

    prep_kernel<<<B / 4, 256, 0, stream>>>(feats, featsN, B);

    int ntiles = B / 128;                      // 64
    int nblocks = ntiles * (ntiles + 1) / 2;   // 2080
    circle_main_kernel<<<nblocks, 512, 0, stream>>>((const unsigned short*)featsN,
                                                    labels, partial, B);

    int nblk = B / 64;  // 128
    rowloss_kernel<<<nblk, 256, 0, stream>>>(partial, blocksum, B);
    final_kernel<<<1, 128, 0, stream>>>(blocksum, out, nblk, B);
}

// Round 22
// 42.967 us; speedup vs baseline: 1.3417x; 1.3417x over previous
//
#include <hip/hip_runtime.h>
#include <math.h>

// CircleLoss, symmetric-triangle bf16-MFMA (R18 anchor) + global_load_lds
// width-16 staging.
//   R21 lesson: wave-count/structure levers exhausted; R18 is the anchor.
//   R22 single delta: staging via __builtin_amdgcn_global_load_lds(16B) —
//   async global->LDS, no VGPR round trip, no ds_write address math.
//   XOR swizzle preserved by pre-swizzling the per-lane GLOBAL column
//   (sc = c ^ (row&15)) with a LINEAR, wave-uniform LDS destination
//   (HW writes base + lane*16). Fragment reads unchanged.
//   Epilogue: u-form + f32x2 packed (P,N) DIRECT accumulation (no T-P
//   cancellation). Triangle (RT<=CT); transposed partial[slot][row] packed
//   bf16; slots col=2RT+wr / row=2CT+wc; LDS-transpose row reduce; parallel
//   rowloss. No atomics, deterministic.
// ws (256MB avail): 2MB featsN + 4MB partial[128][B] + 1KB blocksum.

#define DIM 128
typedef short bf16x8 __attribute__((ext_vector_type(8)));
typedef float f32x4 __attribute__((ext_vector_type(4)));
typedef float f32x2 __attribute__((ext_vector_type(2)));

#if __has_builtin(__builtin_amdgcn_exp2f)
#define EXP2F __builtin_amdgcn_exp2f
#else
#define EXP2F exp2f
#endif

__device__ __forceinline__ unsigned short f2bf(float f) {
    unsigned int b = __float_as_uint(f);
    unsigned int r = (b + 0x7FFFu + ((b >> 16) & 1u)) >> 16;   // RN-even
    return (unsigned short)r;
}
__device__ __forceinline__ unsigned int packPN(float p, float n) {
    return (unsigned int)f2bf(p) | ((unsigned int)f2bf(n) << 16);
}
__device__ __forceinline__ void gload_lds16(const void* g, void* l) {
    __builtin_amdgcn_global_load_lds(
        (const __attribute__((address_space(1))) unsigned int*)g,
        (__attribute__((address_space(3))) unsigned int*)l, 16, 0, 0);
}

// ---------------- Kernel 1: normalize + quantize ----------------
__global__ void prep_kernel(const float* __restrict__ feats,
                            unsigned int* __restrict__ featsN, int B) {
    int wave = (blockIdx.x * blockDim.x + threadIdx.x) >> 6;
    int lane = threadIdx.x & 63;
    if (wave >= B) return;
    const float2* rp = (const float2*)(feats + (size_t)wave * DIM);
    float2 v = rp[lane];
    float s = v.x * v.x + v.y * v.y;
#pragma unroll
    for (int off = 32; off; off >>= 1) s += __shfl_xor(s, off);
    float inv = rsqrtf(s);
    featsN[(size_t)wave * 64 + lane] =
        (unsigned int)f2bf(v.x * inv) | ((unsigned int)f2bf(v.y * inv) << 16);
}

// ---------------- Kernel 2: triangular fused MFMA + masked exp ----------------
// 2080 blocks = tile pairs (RT,CT), RT<=CT. 4 waves in 2x2 of 64x64.
__global__ __launch_bounds__(256, 2) void circle_main_kernel(
    const unsigned short* __restrict__ featsN, const int* __restrict__ labels,
    unsigned int* __restrict__ partial, int B) {
    __shared__ unsigned char smem[65536] __attribute__((aligned(16)));
    unsigned char* Al = smem;
    unsigned char* Bl = smem + 32768;
    unsigned int* tbuf = (unsigned int*)smem;   // transpose scratch, aliases tiles

    // ---- unrank bid -> (RT, CT), RT <= CT ----
    int bid = blockIdx.x;
    int RT = (int)((129.0 - sqrt(16641.0 - 8.0 * (double)bid)) * 0.5);
    RT = RT < 0 ? 0 : (RT > 63 ? 63 : RT);
    while (64 * RT - (RT * (RT - 1)) / 2 > bid) --RT;
    while (64 * (RT + 1) - ((RT + 1) * RT) / 2 <= bid) ++RT;
    const int CT = RT + (bid - (64 * RT - (RT * (RT - 1)) / 2));
    const bool diag = (RT == CT);

    const int tid = threadIdx.x;
    const int lane = tid & 63;
    const int wv = tid >> 6;
    const int wr = wv >> 1, wc = wv & 1;
    const int lg = lane >> 4;
    const int l15 = lane & 15;

    // ---- stage A (RT rows) and B (CT rows) via global_load_lds(16B) ----
    // Wave wv covers rows [wv*32, wv*32+32): 8 groups of 4 rows. Lane lr=l>>4
    // (row in group), c=l&15 (16B slot). Global col pre-swizzled sc=c^(row&15);
    // LDS dest linear+wave-uniform: HW writes base + lane*16 = row*256 + c*16.
    {
        const int lr = lane >> 4, c = lane & 15;
#pragma unroll
        for (int it = 0; it < 8; ++it) {
            int row = wv * 32 + it * 4 + lr;
            int sc = c ^ (row & 15);
            const unsigned short* gA = featsN + (size_t)(RT * 128 + row) * DIM + sc * 8;
            const unsigned short* gB = featsN + (size_t)(CT * 128 + row) * DIM + sc * 8;
            unsigned char* lA = Al + (wv * 32 + it * 4) * 256;   // wave-uniform
            unsigned char* lB = Bl + (wv * 32 + it * 4) * 256;
            gload_lds16(gA, lA);
            gload_lds16(gB, lB);
        }
    }
    __syncthreads();   // compiler emits vmcnt(0) drain before barrier

    // ---- MFMA: 64 per wave (4m x 4n x 4k) ----
    f32x4 acc[4][4];
#pragma unroll
    for (int m = 0; m < 4; ++m)
#pragma unroll
        for (int n = 0; n < 4; ++n) acc[m][n] = (f32x4){0.f, 0.f, 0.f, 0.f};
#pragma unroll
    for (int kk = 0; kk < 4; ++kk) {
        bf16x8 af[4], bfr[4];
#pragma unroll
        for (int m = 0; m < 4; ++m) {
            int row = wr * 64 + m * 16 + l15;
            af[m] = __builtin_bit_cast(bf16x8,
                *(const int4*)(Al + row * 256 + (((kk * 4 + lg) ^ (row & 15)) << 4)));
        }
#pragma unroll
        for (int n = 0; n < 4; ++n) {
            int row = wc * 64 + n * 16 + l15;
            bfr[n] = __builtin_bit_cast(bf16x8,
                *(const int4*)(Bl + row * 256 + (((kk * 4 + lg) ^ (row & 15)) << 4)));
        }
#pragma unroll
        for (int m = 0; m < 4; ++m)
#pragma unroll
            for (int n = 0; n < 4; ++n)
                acc[m][n] = __builtin_amdgcn_mfma_f32_16x16x32_bf16(
                    af[m], bfr[n], acc[m][n], 0, 0, 0);
    }

    // ---- epilogue: u-form, packed (P,N) accumulation ----
    const int rowbase = RT * 128 + wr * 64;
    const int colbase = CT * 128 + wc * 64;
    const float S2 = 46.166241308446828f;   // 32*log2(e)
    const float C2 = -23.083120654223414f;  // -0.5*S2

    int lc[4], lr2[4][4];
#pragma unroll
    for (int n = 0; n < 4; ++n) lc[n] = labels[colbase + n * 16 + l15];
#pragma unroll
    for (int m = 0; m < 4; ++m)
#pragma unroll
        for (int r = 0; r < 4; ++r) lr2[m][r] = labels[rowbase + m * 16 + lg * 4 + r];

    f32x2 rPN[4][4];
    f32x2 cPN[4] = {(f32x2){0.f, 0.f}, (f32x2){0.f, 0.f},
                    (f32x2){0.f, 0.f}, (f32x2){0.f, 0.f}};

    if (diag) {
#pragma unroll
        for (int m = 0; m < 4; ++m) {
#pragma unroll
            for (int r = 0; r < 4; ++r) {
                const int grow = rowbase + m * 16 + lg * 4 + r;
                const int lrow = lr2[m][r];
                f32x2 s_ = (f32x2){0.f, 0.f};
#pragma unroll
                for (int n = 0; n < 4; ++n) {
                    float sim = acc[m][n][r];
                    bool same = (lrow == lc[n]);
                    float u = same ? (1.25f - sim) : (sim + 0.25f);
                    float e2 = fmaxf(u, 0.f) * fmaf(S2, u, C2);
                    float v = EXP2F(e2);
                    bool self = (grow == colbase + n * 16 + l15);
                    v = self ? 0.f : v;             // self excluded everywhere
                    float pv = same ? v : 0.f;
                    s_ += (f32x2){pv, v - pv};      // {P, N} packed add
                }
                rPN[m][r] = s_;
            }
        }
    } else {
#pragma unroll
        for (int m = 0; m < 4; ++m) {
#pragma unroll
            for (int r = 0; r < 4; ++r) {
                const int lrow = lr2[m][r];
                f32x2 s_ = (f32x2){0.f, 0.f};
#pragma unroll
                for (int n = 0; n < 4; ++n) {
                    float sim = acc[m][n][r];
                    bool same = (lrow == lc[n]);
                    float u = same ? (1.25f - sim) : (sim + 0.25f);
                    float e2 = fmaxf(u, 0.f) * fmaf(S2, u, C2);
                    float v = EXP2F(e2);
                    float pv = same ? v : 0.f;
                    f32x2 w = (f32x2){pv, v - pv};  // exact: pv is v or 0
                    s_ += w;
                    cPN[n] += w;
                }
                rPN[m][r] = s_;
            }
        }
    }

    // ---- col partials (off-diag only): shuffle reduce over lane groups ----
    if (!diag) {
#pragma unroll
        for (int n = 0; n < 4; ++n) {
            float p = cPN[n].x, n_ = cPN[n].y;
            p += __shfl_xor(p, 16); p += __shfl_xor(p, 32);
            n_ += __shfl_xor(n_, 16); n_ += __shfl_xor(n_, 32);
            if (lg == 0) {
                int gcol = colbase + n * 16 + l15;
                partial[(size_t)(RT * 2 + wr) * B + gcol] = packPN(p, n_);
            }
        }
    }

    // ---- row partials: LDS transpose reduce (aliased over dead tiles) ----
    __syncthreads();   // all LDS tile reads (MFMA fragments) complete
    {
        unsigned int* T = tbuf + wv * 64 * 17;
#pragma unroll
        for (int m = 0; m < 4; ++m)
#pragma unroll
            for (int r = 0; r < 4; ++r)
                T[(m * 16 + lg * 4 + r) * 17 + l15] = packPN(rPN[m][r].x, rPN[m][r].y);
    }
    __syncthreads();
    {
        const unsigned int* T = tbuf + wv * 64 * 17 + lane * 17;
        float p = 0.f, n_ = 0.f;
#pragma unroll
        for (int c = 0; c < 16; ++c) {
            unsigned int v = T[c];
            p += __uint_as_float(v << 16);
            n_ += __uint_as_float(v & 0xFFFF0000u);
        }
        int grow = RT * 128 + wr * 64 + lane;
        partial[(size_t)(CT * 2 + wc) * B + grow] = packPN(p, n_);
    }
}

// ---------------- Kernel 3: per-row log1p(p*n), parallel over slots ----------------
__global__ void rowloss_kernel(const unsigned int* __restrict__ partial,
                               double* __restrict__ blocksum, int B) {
    __shared__ float2 sdata[64][4];
    int tid = threadIdx.x;
    int r6 = tid & 63, q = tid >> 6;
    int row = blockIdx.x * 64 + r6;
    float p = 0.f, n = 0.f;
#pragma unroll
    for (int c = q * 32; c < q * 32 + 32; ++c) {
        unsigned int v = partial[(size_t)c * B + row];
        p += __uint_as_float(v << 16);
        n += __uint_as_float(v & 0xFFFF0000u);
    }
    sdata[r6][q] = make_float2(p, n);
    __syncthreads();
    if (q == 0) {
        float2 a0 = sdata[r6][0], a1 = sdata[r6][1];
        float2 a2 = sdata[r6][2], a3 = sdata[r6][3];
        double pf = (double)(a0.x + a1.x + a2.x + a3.x);
        double nf = (double)(a0.y + a1.y + a2.y + a3.y);
        double l = log1p(pf * nf);
#pragma unroll
        for (int off = 32; off; off >>= 1) l += __shfl_xor(l, off);
        if (r6 == 0) blocksum[blockIdx.x] = l;
    }
}

__global__ void final_kernel(const double* __restrict__ blocksum,
                             float* __restrict__ out, int nblk, int B) {
    __shared__ double sdata[128];
    int tid = threadIdx.x;
    sdata[tid] = (tid < nblk) ? blocksum[tid] : 0.0;
    __syncthreads();
    for (int s = 64; s; s >>= 1) {
        if (tid < s) sdata[tid] += sdata[tid + s];
        __syncthreads();
    }
    if (tid == 0) out[0] = (float)(sdata[0] / (double)B);
}

extern "C" void kernel_launch(void* const* d_in, const int* in_sizes, int n_in,
                              void* d_out, int out_size, void* d_ws, size_t ws_size,
                              hipStream_t stream) {
    const float* feats = (const float*)d_in[0];
    const int* labels = (const int*)d_in[1];
    float* out = (float*)d_out;
    int B = in_sizes[1];  // 8192

    // ws: featsN bf16 [B][128] (2MB) | partial u32 [128][B] (4MB) | blocksum (1KB)
    unsigned int* featsN = (unsigned int*)d_ws;
    size_t off1 = ((size_t)B * DIM * 2 + 255) & ~(size_t)255;
    unsigned int* partial = (unsigned int*)((char*)d_ws + off1);
    size_t off2 = off1 + (((size_t)B * 128 * sizeof(unsigned int) + 255) & ~(size_t)255);
    double* blocksum = (double*)((char*)d_ws + off2);

    prep_kernel<<<B / 4, 256, 0, stream>>>(feats, featsN, B);

    int ntiles = B / 128;                      // 64
    int nblocks = ntiles * (ntiles + 1) / 2;   // 2080
    circle_main_kernel<<<nblocks, 256, 0, stream>>>((const unsigned short*)featsN,
                                                    labels, partial, B);

    int nblk = B / 64;  // 128
    rowloss_kernel<<<nblk, 256, 0, stream>>>(partial, blocksum, B);
    final_kernel<<<1, 128, 0, stream>>>(blocksum, out, nblk, B);
}

// Round 23
// 42.477 us; speedup vs baseline: 1.3572x; 1.0115x over previous
//
#include <hip/hip_runtime.h>
#include <math.h>

// CircleLoss, symmetric-triangle bf16-MFMA (R18 FINAL — best validated, 42.28us).
//   Pipeline: prep (normalize f32->bf16) -> main (triangular 128x128 tile-pair
//   MFMA sim + fused u-form masked-exp epilogue, f32x2-packed DIRECT (P,N)
//   accumulation, LDS-transpose row reduce, transposed packed-bf16 partials)
//   -> parallel rowloss -> final mean.
//   Roofline note: main kernel ~31us ~= 87% of its serialized issue-sum floor
//   (7.9K cyc/wave x 8.1 block-waves/SIMD); all pipes <55% individually;
//   6 structural variants landed 31-33us. Dependency-bound, not resource-bound.
// ws (256MB avail): 2MB featsN + 4MB partial[128][B] + 1KB blocksum.

#define DIM 128
typedef short bf16x8 __attribute__((ext_vector_type(8)));
typedef float f32x4 __attribute__((ext_vector_type(4)));
typedef float f32x2 __attribute__((ext_vector_type(2)));

#if __has_builtin(__builtin_amdgcn_exp2f)
#define EXP2F __builtin_amdgcn_exp2f
#else
#define EXP2F exp2f
#endif

__device__ __forceinline__ unsigned short f2bf(float f) {
    unsigned int b = __float_as_uint(f);
    unsigned int r = (b + 0x7FFFu + ((b >> 16) & 1u)) >> 16;   // RN-even
    return (unsigned short)r;
}
__device__ __forceinline__ unsigned int packPN(float p, float n) {
    return (unsigned int)f2bf(p) | ((unsigned int)f2bf(n) << 16);
}

// ---------------- Kernel 1: normalize + quantize ----------------
__global__ void prep_kernel(const float* __restrict__ feats,
                            unsigned int* __restrict__ featsN, int B) {
    int wave = (blockIdx.x * blockDim.x + threadIdx.x) >> 6;
    int lane = threadIdx.x & 63;
    if (wave >= B) return;
    const float2* rp = (const float2*)(feats + (size_t)wave * DIM);
    float2 v = rp[lane];
    float s = v.x * v.x + v.y * v.y;
#pragma unroll
    for (int off = 32; off; off >>= 1) s += __shfl_xor(s, off);
    float inv = rsqrtf(s);
    featsN[(size_t)wave * 64 + lane] =
        (unsigned int)f2bf(v.x * inv) | ((unsigned int)f2bf(v.y * inv) << 16);
}

// ---------------- Kernel 2: triangular fused MFMA + masked exp ----------------
// 2080 blocks = tile pairs (RT,CT), RT<=CT. 4 waves in 2x2 of 64x64.
__global__ __launch_bounds__(256, 2) void circle_main_kernel(
    const unsigned short* __restrict__ featsN, const int* __restrict__ labels,
    unsigned int* __restrict__ partial, int B) {
    __shared__ unsigned char smem[65536] __attribute__((aligned(16)));
    unsigned char* Al = smem;
    unsigned char* Bl = smem + 32768;
    unsigned int* tbuf = (unsigned int*)smem;   // transpose scratch, aliases tiles

    // ---- unrank bid -> (RT, CT), RT <= CT ----
    int bid = blockIdx.x;
    int RT = (int)((129.0 - sqrt(16641.0 - 8.0 * (double)bid)) * 0.5);
    RT = RT < 0 ? 0 : (RT > 63 ? 63 : RT);
    while (64 * RT - (RT * (RT - 1)) / 2 > bid) --RT;
    while (64 * (RT + 1) - ((RT + 1) * RT) / 2 <= bid) ++RT;
    const int CT = RT + (bid - (64 * RT - (RT * (RT - 1)) / 2));
    const bool diag = (RT == CT);

    const int tid = threadIdx.x;
    const int lane = tid & 63;
    const int wv = tid >> 6;
    const int wr = wv >> 1, wc = wv & 1;
    const int lg = lane >> 4;
    const int l15 = lane & 15;

    // ---- stage A (RT rows) and B (CT rows), 4-bit XOR swizzle ----
    {
        const int r0 = tid >> 4, c = tid & 15;
#pragma unroll
        for (int it = 0; it < 8; ++it) {
            int row = it * 16 + r0;
            int swz = ((c ^ (row & 15)) << 4);
            int4 va = *(const int4*)(featsN + (size_t)(RT * 128 + row) * DIM + c * 8);
            *(int4*)(Al + row * 256 + swz) = va;
            int4 vb = *(const int4*)(featsN + (size_t)(CT * 128 + row) * DIM + c * 8);
            *(int4*)(Bl + row * 256 + swz) = vb;
        }
    }
    __syncthreads();

    // ---- MFMA: 64 per wave (4m x 4n x 4k) ----
    f32x4 acc[4][4];
#pragma unroll
    for (int m = 0; m < 4; ++m)
#pragma unroll
        for (int n = 0; n < 4; ++n) acc[m][n] = (f32x4){0.f, 0.f, 0.f, 0.f};
#pragma unroll
    for (int kk = 0; kk < 4; ++kk) {
        bf16x8 af[4], bfr[4];
#pragma unroll
        for (int m = 0; m < 4; ++m) {
            int row = wr * 64 + m * 16 + l15;
            af[m] = __builtin_bit_cast(bf16x8,
                *(const int4*)(Al + row * 256 + (((kk * 4 + lg) ^ (row & 15)) << 4)));
        }
#pragma unroll
        for (int n = 0; n < 4; ++n) {
            int row = wc * 64 + n * 16 + l15;
            bfr[n] = __builtin_bit_cast(bf16x8,
                *(const int4*)(Bl + row * 256 + (((kk * 4 + lg) ^ (row & 15)) << 4)));
        }
#pragma unroll
        for (int m = 0; m < 4; ++m)
#pragma unroll
            for (int n = 0; n < 4; ++n)
                acc[m][n] = __builtin_amdgcn_mfma_f32_16x16x32_bf16(
                    af[m], bfr[n], acc[m][n], 0, 0, 0);
    }

    // ---- epilogue: u-form, packed (P,N) accumulation ----
    const int rowbase = RT * 128 + wr * 64;
    const int colbase = CT * 128 + wc * 64;
    const float S2 = 46.166241308446828f;   // 32*log2(e)
    const float C2 = -23.083120654223414f;  // -0.5*S2

    int lc[4], lr[4][4];
#pragma unroll
    for (int n = 0; n < 4; ++n) lc[n] = labels[colbase + n * 16 + l15];
#pragma unroll
    for (int m = 0; m < 4; ++m)
#pragma unroll
        for (int r = 0; r < 4; ++r) lr[m][r] = labels[rowbase + m * 16 + lg * 4 + r];

    f32x2 rPN[4][4];
    f32x2 cPN[4] = {(f32x2){0.f, 0.f}, (f32x2){0.f, 0.f},
                    (f32x2){0.f, 0.f}, (f32x2){0.f, 0.f}};

    if (diag) {
#pragma unroll
        for (int m = 0; m < 4; ++m) {
#pragma unroll
            for (int r = 0; r < 4; ++r) {
                const int grow = rowbase + m * 16 + lg * 4 + r;
                const int lrow = lr[m][r];
                f32x2 s_ = (f32x2){0.f, 0.f};
#pragma unroll
                for (int n = 0; n < 4; ++n) {
                    float sim = acc[m][n][r];
                    bool same = (lrow == lc[n]);
                    float u = same ? (1.25f - sim) : (sim + 0.25f);
                    float e2 = fmaxf(u, 0.f) * fmaf(S2, u, C2);
                    float v = EXP2F(e2);
                    bool self = (grow == colbase + n * 16 + l15);
                    v = self ? 0.f : v;             // self excluded everywhere
                    float pv = same ? v : 0.f;
                    s_ += (f32x2){pv, v - pv};      // {P, N} packed add
                }
                rPN[m][r] = s_;
            }
        }
    } else {
#pragma unroll
        for (int m = 0; m < 4; ++m) {
#pragma unroll
            for (int r = 0; r < 4; ++r) {
                const int lrow = lr[m][r];
                f32x2 s_ = (f32x2){0.f, 0.f};
#pragma unroll
                for (int n = 0; n < 4; ++n) {
                    float sim = acc[m][n][r];
                    bool same = (lrow == lc[n]);
                    float u = same ? (1.25f - sim) : (sim + 0.25f);
                    float e2 = fmaxf(u, 0.f) * fmaf(S2, u, C2);
                    float v = EXP2F(e2);
                    float pv = same ? v : 0.f;
                    f32x2 w = (f32x2){pv, v - pv};  // exact: pv is v or 0
                    s_ += w;
                    cPN[n] += w;
                }
                rPN[m][r] = s_;
            }
        }
    }

    // ---- col partials (off-diag only): shuffle reduce over lane groups ----
    if (!diag) {
#pragma unroll
        for (int n = 0; n < 4; ++n) {
            float p = cPN[n].x, n_ = cPN[n].y;
            p += __shfl_xor(p, 16); p += __shfl_xor(p, 32);
            n_ += __shfl_xor(n_, 16); n_ += __shfl_xor(n_, 32);
            if (lg == 0) {
                int gcol = colbase + n * 16 + l15;
                partial[(size_t)(RT * 2 + wr) * B + gcol] = packPN(p, n_);
            }
        }
    }

    // ---- row partials: LDS transpose reduce (aliased over dead tiles) ----
    __syncthreads();   // all LDS tile reads (MFMA fragments) complete
    {
        unsigned int* T = tbuf + wv * 64 * 17;
#pragma unroll
        for (int m = 0; m < 4; ++m)
#pragma unroll
            for (int r = 0; r < 4; ++r)
                T[(m * 16 + lg * 4 + r) * 17 + l15] = packPN(rPN[m][r].x, rPN[m][r].y);
    }
    __syncthreads();
    {
        const unsigned int* T = tbuf + wv * 64 * 17 + lane * 17;
        float p = 0.f, n_ = 0.f;
#pragma unroll
        for (int c = 0; c < 16; ++c) {
            unsigned int v = T[c];
            p += __uint_as_float(v << 16);
            n_ += __uint_as_float(v & 0xFFFF0000u);
        }
        int grow = RT * 128 + wr * 64 + lane;
        partial[(size_t)(CT * 2 + wc) * B + grow] = packPN(p, n_);
    }
}

// ---------------- Kernel 3: per-row log1p(p*n), parallel over slots ----------------
__global__ void rowloss_kernel(const unsigned int* __restrict__ partial,
                               double* __restrict__ blocksum, int B) {
    __shared__ float2 sdata[64][4];
    int tid = threadIdx.x;
    int r6 = tid & 63, q = tid >> 6;
    int row = blockIdx.x * 64 + r6;
    float p = 0.f, n = 0.f;
#pragma unroll
    for (int c = q * 32; c < q * 32 + 32; ++c) {
        unsigned int v = partial[(size_t)c * B + row];
        p += __uint_as_float(v << 16);
        n += __uint_as_float(v & 0xFFFF0000u);
    }
    sdata[r6][q] = make_float2(p, n);
    __syncthreads();
    if (q == 0) {
        float2 a0 = sdata[r6][0], a1 = sdata[r6][1];
        float2 a2 = sdata[r6][2], a3 = sdata[r6][3];
        double pf = (double)(a0.x + a1.x + a2.x + a3.x);
        double nf = (double)(a0.y + a1.y + a2.y + a3.y);
        double l = log1p(pf * nf);
#pragma unroll
        for (int off = 32; off; off >>= 1) l += __shfl_xor(l, off);
        if (r6 == 0) blocksum[blockIdx.x] = l;
    }
}

__global__ void final_kernel(const double* __restrict__ blocksum,
                             float* __restrict__ out, int nblk, int B) {
    __shared__ double sdata[128];
    int tid = threadIdx.x;
    sdata[tid] = (tid < nblk) ? blocksum[tid] : 0.0;
    __syncthreads();
    for (int s = 64; s; s >>= 1) {
        if (tid < s) sdata[tid] += sdata[tid + s];
        __syncthreads();
    }
    if (tid == 0) out[0] = (float)(sdata[0] / (double)B);
}

extern "C" void kernel_launch(void* const* d_in, const int* in_sizes, int n_in,
                              void* d_out, int out_size, void* d_ws, size_t ws_size,
                              hipStream_t stream) {
    const float* feats = (const float*)d_in[0];
    const int* labels = (const int*)d_in[1];
    float* out = (float*)d_out;
    int B = in_sizes[1];  // 8192

    // ws: featsN bf16 [B][128] (2MB) | partial u32 [128][B] (4MB) | blocksum (1KB)
    unsigned int* featsN = (unsigned int*)d_ws;
    size_t off1 = ((size_t)B * DIM * 2 + 255) & ~(size_t)255;
    unsigned int* partial = (unsigned int*)((char*)d_ws + off1);
    size_t off2 = off1 + (((size_t)B * 128 * sizeof(unsigned int) + 255) & ~(size_t)255);
    double* blocksum = (double*)((char*)d_ws + off2);

    prep_kernel<<<B / 4, 256, 0, stream>>>(feats, featsN, B);

    int ntiles = B / 128;                      // 64
    int nblocks = ntiles * (ntiles + 1) / 2;   // 2080
    circle_main_kernel<<<nblocks, 256, 0, stream>>>((const unsigned short*)featsN,
                                                    labels, partial, B);

    int nblk = B / 64;  // 128
    rowloss_kernel<<<nblk, 256, 0, stream>>>(partial, blocksum, B);
    final_kernel<<<1, 128, 0, stream>>>(blocksum, out, nblk, B);
}